// Round 4
// baseline (475.912 us; speedup 1.0000x reference)
//
#include <hip/hip_runtime.h>

// SSIM loss, fused: (32,3,512,512) fp32, 11x11 avg pools, out = 1 - mean(ssim_map).
//
// R4: occupancy-first restructure. One block = 64x16 output tile.
//  H = (Sum p, Sum t, Sum p^2+t^2, Sum p*t) per cell -> float4 in LDS,
//  26 halo rows x 64 cols, stride 65 float4 -> 27 KB -> 5 blocks/CU
//  (__launch_bounds__(256,5), VGPR cap 102) = 20 waves/CU vs R3's 12.
//  Stage B: thread = (halo row j, 8-col run rn), 208/256 threads.
//    6 aligned float4 loads per tensor covering [x0-8, x0+16), horizontal
//    11-window slid in registers, 8 float4 LDS writes.
//  Stage C: lane = x (contiguous b128 reads, measured-conflict-free pattern),
//    wave w owns 4 output rows, 10-row running sum in registers; 14 taps / 4 px.
//  Block reduce -> atomicAdd(double); finalize: out = 1 - sum/N.

#define IMGW 512
#define IMGPIX (IMGW * IMGW)
#define TW 64
#define TH 16
#define NROWS 26          // TH + 10 halo
#define SH 65             // LDS row stride in float4
#define NIMG 96

__global__ __launch_bounds__(256, 5)
void ssim_partial(const float* __restrict__ pred,
                  const float* __restrict__ target,
                  double* __restrict__ accum)
{
    __shared__ float4 sH[NROWS * SH];   // 27040 B
    __shared__ float  wpart[4];

    const int tid = threadIdx.x;
    const int bx = blockIdx.x, by = blockIdx.y, img = blockIdx.z;
    const float* __restrict__ p = pred   + (size_t)img * IMGPIX;
    const float* __restrict__ t = target + (size_t)img * IMGPIX;
    const int gy0 = by * TH;

    // ---- Stage B: horizontal 11-sums, sliding in registers ----
    if (tid < NROWS * 8) {
        const int j  = tid >> 3;          // halo row 0..25
        const int rn = tid & 7;           // 8-col run
        const int rv = gy0 - 5 + j;       // image row (OOB -> zero row)
        const bool rowok = (unsigned)rv < (unsigned)IMGW;
        const int xbase = bx * TW + rn * 8;

        float fp[24], ft[24];
#pragma unroll
        for (int c = 0; c < 6; ++c) {
            const int gx = xbase - 8 + 4 * c;     // multiple of 4 -> aligned float4
            float4 pv = {0.f, 0.f, 0.f, 0.f};
            float4 tv = {0.f, 0.f, 0.f, 0.f};
            if (rowok && (unsigned)gx < (unsigned)IMGW) {
                const size_t off = (size_t)rv * IMGW + gx;
                pv = *(const float4*)(p + off);
                tv = *(const float4*)(t + off);
            }
            fp[4*c+0] = pv.x; fp[4*c+1] = pv.y; fp[4*c+2] = pv.z; fp[4*c+3] = pv.w;
            ft[4*c+0] = tv.x; ft[4*c+1] = tv.y; ft[4*c+2] = tv.z; ft[4*c+3] = tv.w;
        }
        // output x = xbase+k has window indices i = k+3 .. k+13 (x = xbase-8+i)
        float s1 = 0.f, s2 = 0.f, s3 = 0.f, s4 = 0.f;
#pragma unroll
        for (int i = 3; i <= 13; ++i) {
            s1 += fp[i];
            s2 += ft[i];
            s3 += fp[i] * fp[i] + ft[i] * ft[i];
            s4 += fp[i] * ft[i];
        }
        const int lbase = j * SH + rn * 8;
#pragma unroll
        for (int k = 0; k < 8; ++k) {
            if (k > 0) {
                const int a = k + 13, b = k + 2;
                s1 += fp[a] - fp[b];
                s2 += ft[a] - ft[b];
                s3 += (fp[a] * fp[a] + ft[a] * ft[a])
                    - (fp[b] * fp[b] + ft[b] * ft[b]);
                s4 += fp[a] * ft[a] - fp[b] * ft[b];
            }
            sH[lbase + k] = make_float4(s1, s2, s3, s4);
        }
    }
    __syncthreads();

    // ---- Stage C: vertical 11-sums (lane = x), SSIM formula ----
    const float inv = 1.0f / 121.0f;
    const float C1 = 1e-4f, C2 = 9e-4f;
    const int lane = tid & 63;
    const int w    = tid >> 6;
    const int r0   = w * 4;               // 4 output rows per wave

    float4 r[4];
    float4 S = {0.f, 0.f, 0.f, 0.f};
#pragma unroll
    for (int i = 0; i < 4; ++i) {
        r[i] = sH[(r0 + i) * SH + lane];
        S.x += r[i].x; S.y += r[i].y; S.z += r[i].z; S.w += r[i].w;
    }
#pragma unroll
    for (int i = 4; i < 10; ++i) {
        const float4 a = sH[(r0 + i) * SH + lane];
        S.x += a.x; S.y += a.y; S.z += a.z; S.w += a.w;
    }
    float local = 0.f;
#pragma unroll
    for (int k = 0; k < 4; ++k) {
        const float4 nw = sH[(r0 + 10 + k) * SH + lane];
        const float W1 = S.x + nw.x;      // 11-row window sums
        const float W2 = S.y + nw.y;
        const float W3 = S.z + nw.z;
        const float W4 = S.w + nw.w;
        S.x = W1 - r[k].x; S.y = W2 - r[k].y;
        S.z = W3 - r[k].z; S.w = W4 - r[k].w;

        const float mu1 = W1 * inv, mu2 = W2 * inv;
        const float E3  = W3 * inv, E12 = W4 * inv;
        const float mu11 = mu1 * mu1, mu22 = mu2 * mu2, mu12 = mu1 * mu2;
        const float num = (2.f * mu12 + C1) * (2.f * (E12 - mu12) + C2);
        const float den = (mu11 + mu22 + C1) * ((E3 - mu11 - mu22) + C2);
        local += num / den;
    }

    // ---- block reduce -> one double atomic per block ----
#pragma unroll
    for (int off = 32; off > 0; off >>= 1)
        local += __shfl_down(local, off, 64);
    if ((tid & 63) == 0) wpart[tid >> 6] = local;
    __syncthreads();
    if (tid == 0)
        atomicAdd(accum, (double)(wpart[0] + wpart[1] + wpart[2] + wpart[3]));
}

__global__ void ssim_finalize(const double* __restrict__ accum,
                              float* __restrict__ out) {
    const double n = 25165824.0;  // 32*3*512*512
    out[0] = (float)(1.0 - accum[0] / n);
}

extern "C" void kernel_launch(void* const* d_in, const int* in_sizes, int n_in,
                              void* d_out, int out_size, void* d_ws, size_t ws_size,
                              hipStream_t stream) {
    const float* pred   = (const float*)d_in[0];
    const float* target = (const float*)d_in[1];
    float* out = (float*)d_out;
    double* accum = (double*)d_ws;

    hipMemsetAsync(d_ws, 0, sizeof(double), stream);

    dim3 grid(IMGW / TW, IMGW / TH, NIMG);  // 8 x 32 x 96
    dim3 block(256);
    ssim_partial<<<grid, block, 0, stream>>>(pred, target, accum);
    ssim_finalize<<<1, 1, 0, stream>>>(accum, out);
}

// Round 5
// 319.937 us; speedup vs baseline: 1.4875x; 1.4875x over previous
//
#include <hip/hip_runtime.h>

// SSIM loss, fused: (32,3,512,512) fp32, 11x11 avg pools, out = 1 - mean(ssim_map).
//
// R5 = R3 structure + XOR-swizzled LDS columns (fixes 8-way bank-conflicted
// stage-B writes measured at 2.3-3.6e7 conflict cycles in R2/R4).
//
//  H = (Sum p, Sum t, Sum p^2+t^2, Sum pt) per cell -> float4 in LDS.
//  Layout: sH[row * 64 + (x ^ (row & 7))]. At fixed write step k, bank group
//  = (k ^ (j&7)) mod 8 -> uniform over the wave's 16 j's (8 lanes/group,
//  the b128 minimum). Stage-C reads a bijective permutation of 64 contiguous
//  float4s per row -> uniform. Cost: 1 XOR per access.
//
//  Stage B (horizontal 11-sums): thread = (halo row j of 42, 16-col run xr of 4),
//    168/256 active. 8 aligned float4 loads per tensor (independent,
//    vmcnt-pipelined), window slid in registers, 16 swizzled float4 writes.
//  Stage C (vertical 11-sums): lane = x, wave owns 8 output rows, 10-row
//    running sum in registers, 1 new b128 tap per px.
//  Block reduce -> atomicAdd(double); finalize: out = 1 - sum/N.

#define IMGW 512
#define IMGPIX (IMGW * IMGW)
#define TW 64
#define TH 32
#define NROWS 42          // TH + 10 halo
#define SH 64             // LDS row stride in float4 (swizzle replaces padding)
#define NIMG 96

__global__ __launch_bounds__(256, 3)
void ssim_partial(const float* __restrict__ pred,
                  const float* __restrict__ target,
                  double* __restrict__ accum)
{
    __shared__ float4 sH[NROWS * SH];   // 43008 B
    __shared__ float  wpart[4];

    const int tid = threadIdx.x;
    const int bx = blockIdx.x, by = blockIdx.y, img = blockIdx.z;
    const float* __restrict__ p = pred   + (size_t)img * IMGPIX;
    const float* __restrict__ t = target + (size_t)img * IMGPIX;
    const int gy0 = by * TH;

    // ---- Stage B: horizontal 11-sums of 4 planes, sliding in registers ----
    if (tid < NROWS * 4) {
        const int j  = tid >> 2;          // halo row 0..41
        const int xr = tid & 3;           // 16-col run
        const int rv = gy0 - 5 + j;       // image row (OOB -> zero row)
        const bool rowok = (unsigned)rv < (unsigned)IMGW;
        const int xbase = bx * TW + xr * 16;

        float fp[32], ft[32];
#pragma unroll
        for (int c = 0; c < 8; ++c) {
            const int gx = xbase - 8 + 4 * c;     // multiple of 4 -> aligned float4
            float4 pv = {0.f, 0.f, 0.f, 0.f};
            float4 tv = {0.f, 0.f, 0.f, 0.f};
            if (rowok && (unsigned)gx < (unsigned)IMGW) {
                const size_t off = (size_t)rv * IMGW + gx;
                pv = *(const float4*)(p + off);
                tv = *(const float4*)(t + off);
            }
            fp[4*c+0] = pv.x; fp[4*c+1] = pv.y; fp[4*c+2] = pv.z; fp[4*c+3] = pv.w;
            ft[4*c+0] = tv.x; ft[4*c+1] = tv.y; ft[4*c+2] = tv.z; ft[4*c+3] = tv.w;
        }
        // output x = xbase+k has window indices i = k+3 .. k+13 (x = xbase-8+i)
        float s1 = 0.f, s2 = 0.f, s3 = 0.f, s4 = 0.f;
#pragma unroll
        for (int i = 3; i <= 13; ++i) {
            s1 += fp[i];
            s2 += ft[i];
            s3 += fp[i] * fp[i] + ft[i] * ft[i];
            s4 += fp[i] * ft[i];
        }
        const int jb   = j * SH;
        const int cxor = j & 7;
        const int xb   = xr * 16;
#pragma unroll
        for (int k = 0; k < 16; ++k) {
            if (k > 0) {
                const int a = k + 13, b = k + 2;
                s1 += fp[a] - fp[b];
                s2 += ft[a] - ft[b];
                s3 += (fp[a] * fp[a] + ft[a] * ft[a])
                    - (fp[b] * fp[b] + ft[b] * ft[b]);
                s4 += fp[a] * ft[a] - fp[b] * ft[b];
            }
            sH[jb + ((xb + k) ^ cxor)] = make_float4(s1, s2, s3, s4);
        }
    }
    __syncthreads();

    // ---- Stage C: vertical 11-sums (lane = x, swizzled reads), SSIM ----
    const float inv = 1.0f / 121.0f;
    const float C1 = 1e-4f, C2 = 9e-4f;
    const int lane = tid & 63;
    const int w    = tid >> 6;
    const int r0   = w * 8;               // 8 output rows per wave

    float4 r[8];
    float4 S = {0.f, 0.f, 0.f, 0.f};
#pragma unroll
    for (int i = 0; i < 8; ++i) {
        const int row = r0 + i;
        r[i] = sH[row * SH + (lane ^ (row & 7))];
        S.x += r[i].x; S.y += r[i].y; S.z += r[i].z; S.w += r[i].w;
    }
#pragma unroll
    for (int i = 8; i < 10; ++i) {
        const int row = r0 + i;
        const float4 a = sH[row * SH + (lane ^ (row & 7))];
        S.x += a.x; S.y += a.y; S.z += a.z; S.w += a.w;
    }
    float local = 0.f;
#pragma unroll
    for (int k = 0; k < 8; ++k) {
        const int row = r0 + 10 + k;
        const float4 nw = sH[row * SH + (lane ^ (row & 7))];
        const float W1 = S.x + nw.x;      // 11-row window sums
        const float W2 = S.y + nw.y;
        const float W3 = S.z + nw.z;
        const float W4 = S.w + nw.w;
        S.x = W1 - r[k].x; S.y = W2 - r[k].y;
        S.z = W3 - r[k].z; S.w = W4 - r[k].w;

        const float mu1 = W1 * inv, mu2 = W2 * inv;
        const float E3  = W3 * inv, E12 = W4 * inv;
        const float mu11 = mu1 * mu1, mu22 = mu2 * mu2, mu12 = mu1 * mu2;
        const float num = (2.f * mu12 + C1) * (2.f * (E12 - mu12) + C2);
        const float den = (mu11 + mu22 + C1) * ((E3 - mu11 - mu22) + C2);
        local += num / den;
    }

    // ---- block reduce -> one double atomic per block ----
#pragma unroll
    for (int off = 32; off > 0; off >>= 1)
        local += __shfl_down(local, off, 64);
    if ((tid & 63) == 0) wpart[tid >> 6] = local;
    __syncthreads();
    if (tid == 0)
        atomicAdd(accum, (double)(wpart[0] + wpart[1] + wpart[2] + wpart[3]));
}

__global__ void ssim_finalize(const double* __restrict__ accum,
                              float* __restrict__ out) {
    const double n = 25165824.0;  // 32*3*512*512
    out[0] = (float)(1.0 - accum[0] / n);
}

extern "C" void kernel_launch(void* const* d_in, const int* in_sizes, int n_in,
                              void* d_out, int out_size, void* d_ws, size_t ws_size,
                              hipStream_t stream) {
    const float* pred   = (const float*)d_in[0];
    const float* target = (const float*)d_in[1];
    float* out = (float*)d_out;
    double* accum = (double*)d_ws;

    hipMemsetAsync(d_ws, 0, sizeof(double), stream);

    dim3 grid(IMGW / TW, IMGW / TH, NIMG);  // 8 x 16 x 96
    dim3 block(256);
    ssim_partial<<<grid, block, 0, stream>>>(pred, target, accum);
    ssim_finalize<<<1, 1, 0, stream>>>(accum, out);
}